// Round 5
// baseline (137.578 us; speedup 1.0000x reference)
//
#include <hip/hip_runtime.h>

#define GRID_N 16384
#define NLAYERS 8
#define NPOS 32
#define BATCH 32
#define MW 4096          // output width
#define TILE 32
#define HALO 16          // 2 * NLAYERS
#define WBUF 64          // TILE + 2*HALO
#define ROWP 36          // padded row stride: 144B, 16B-aligned, full-BW rotation pattern

// v5 = v4 kernel byte-identical; kernel_launch fires it 4x (idempotent) as a
// DIFFERENTIAL TIMING PROBE: dur_us - 82 ≈ 3*K resolves the kernel's true
// device time, which the rocprof top-5 cutoff (42.4 µs ws-poison fills) hides.
__global__ __launch_bounds__(512, 4) void ASIC_44186623541335_kernel(
    const float* __restrict__ x,    // (32, 4096)
    const float* __restrict__ tg,   // (8, 32, 16384) raw logits
    float* __restrict__ out)        // (32, 4096)
{
    __shared__ __align__(16) float st[WBUF][ROWP];        // 9.2 KB, single buffer
    __shared__ __align__(16) float twl[4][WBUF][ROWP];    // 36.9 KB, 4 layers of gates

    const int tid = threadIdx.x;
    const int tx  = tid & 63;        // column slot (lane)
    const int ty  = tid >> 6;        // 0..7 -> batches 4ty..4ty+3, gate cols 4ty..4ty+3
    const int c0  = 4 * ty;
    const int start = blockIdx.x * TILE;
    const int gcol  = (start - HALO + tx) & (GRID_N - 1);

    // ---- prefetch gate logits for layers 0..3 (coalesced across lanes) ----
    float pf[16];
    #pragma unroll
    for (int l4 = 0; l4 < 4; ++l4)
        #pragma unroll
        for (int k = 0; k < 4; ++k)
            pf[l4 * 4 + k] = tg[((size_t)l4 * NPOS + c0 + k) * GRID_N + gcol];

    // ---- init state: embed x at stride 4, zeros elsewhere ----
    for (int f = tid; f < WBUF * BATCH; f += 512) {
        const int b = f >> 6;        // batch
        const int j = f & 63;        // column slot (lane-consecutive -> coalesced x)
        const int g = (start - HALO + j) & (GRID_N - 1);
        st[j][b] = ((g & 3) == 0) ? x[b * MW + (g >> 2)] : 0.0f;
    }

    // ---- stage layers 0..3 (sigmoid once), prefetch layers 4..7 ----
    #pragma unroll
    for (int l4 = 0; l4 < 4; ++l4) {
        float4 sg;
        sg.x = __builtin_amdgcn_rcpf(1.0f + __expf(-pf[l4 * 4 + 0]));
        sg.y = __builtin_amdgcn_rcpf(1.0f + __expf(-pf[l4 * 4 + 1]));
        sg.z = __builtin_amdgcn_rcpf(1.0f + __expf(-pf[l4 * 4 + 2]));
        sg.w = __builtin_amdgcn_rcpf(1.0f + __expf(-pf[l4 * 4 + 3]));
        *(float4*)&twl[l4][tx][c0] = sg;
    }
    #pragma unroll
    for (int l4 = 0; l4 < 4; ++l4)
        #pragma unroll
        for (int k = 0; k < 4; ++k)
            pf[l4 * 4 + k] = tg[((size_t)(4 + l4) * NPOS + c0 + k) * GRID_N + gcol];
    __syncthreads();   // barrier 1: gates(0..3) + embedded state visible

    for (int l = 0; l < NLAYERS; ++l) {
        const int h     = 2 * (NLAYERS - 1 - l);
        const int ncols = TILE + 2 * h;          // 60,56,...,32
        const int j     = (HALO - h) + tx;

        if (tx < ncols) {
            // gates for this column -> 32 regs (8x ds_read_b128)
            float tw[32];
            #pragma unroll
            for (int k = 0; k < 8; ++k) {
                const float4 q = *(const float4*)&twl[l & 3][j][4 * k];
                tw[4 * k]     = q.x; tw[4 * k + 1] = q.y;
                tw[4 * k + 2] = q.z; tw[4 * k + 3] = q.w;
            }

            float4 res;
            #pragma unroll
            for (int p = 0; p < 2; ++p) {
                // per-pair state loads (b64): 2 batches x 5 neighbor columns
                const float2 S0 = *(const float2*)&st[j - 2][c0 + 2 * p];
                const float2 S1 = *(const float2*)&st[j - 1][c0 + 2 * p];
                const float2 S2 = *(const float2*)&st[j    ][c0 + 2 * p];
                const float2 S3 = *(const float2*)&st[j + 1][c0 + 2 * p];
                const float2 S4 = *(const float2*)&st[j + 2][c0 + 2 * p];

                // 5-level lerp tree == multilinear interpolation of tw
                float ua[16], ub[16];
                #pragma unroll
                for (int r = 0; r < 16; ++r) {
                    const float d = tw[16 + r] - tw[r];   // batch-invariant
                    ua[r] = fmaf(S0.x, d, tw[r]);
                    ub[r] = fmaf(S0.y, d, tw[r]);
                }
                #pragma unroll
                for (int r = 0; r < 8; ++r) {
                    const float da = ua[8 + r] - ua[r], db = ub[8 + r] - ub[r];
                    ua[r] = fmaf(S1.x, da, ua[r]);
                    ub[r] = fmaf(S1.y, db, ub[r]);
                }
                #pragma unroll
                for (int r = 0; r < 4; ++r) {
                    const float da = ua[4 + r] - ua[r], db = ub[4 + r] - ub[r];
                    ua[r] = fmaf(S2.x, da, ua[r]);
                    ub[r] = fmaf(S2.y, db, ub[r]);
                }
                #pragma unroll
                for (int r = 0; r < 2; ++r) {
                    const float da = ua[2 + r] - ua[r], db = ub[2 + r] - ub[r];
                    ua[r] = fmaf(S3.x, da, ua[r]);
                    ub[r] = fmaf(S3.y, db, ub[r]);
                }
                const float da = ua[1] - ua[0], db = ub[1] - ub[0];
                float ra = fmaf(S4.x, da, ua[0]);
                float rb = fmaf(S4.y, db, ub[0]);
                ra = fminf(fmaxf(ra, 0.0f), 1.0f);
                rb = fminf(fmaxf(rb, 0.0f), 1.0f);
                if (p) { res.z = ra; res.w = rb; } else { res.x = ra; res.y = rb; }
            }
            *(float4*)&st[j][c0] = res;   // wave-private slice: no barrier needed
        }
        // forbid compiler hoisting next layer's LDS reads above this write;
        // HW executes a wave's DS ops in order, so cross-lane RAW is safe.
        __builtin_amdgcn_wave_barrier();

        if (l == 3) {
            __syncthreads();   // barrier 2: everyone done reading gates(0..3)
            #pragma unroll
            for (int l4 = 0; l4 < 4; ++l4) {
                float4 sg;
                sg.x = __builtin_amdgcn_rcpf(1.0f + __expf(-pf[l4 * 4 + 0]));
                sg.y = __builtin_amdgcn_rcpf(1.0f + __expf(-pf[l4 * 4 + 1]));
                sg.z = __builtin_amdgcn_rcpf(1.0f + __expf(-pf[l4 * 4 + 2]));
                sg.w = __builtin_amdgcn_rcpf(1.0f + __expf(-pf[l4 * 4 + 3]));
                *(float4*)&twl[l4][tx][c0] = sg;
            }
            __syncthreads();   // barrier 3: gates(4..7) visible
        }
    }

    __syncthreads();           // barrier 4: final state visible for transposed output
    // ---- output: state[:, ::4] for this tile's 32 owned columns ----
    if (tid < 256) {
        const int c4 = tid & 7;          // output column within tile
        const int b  = tid >> 3;         // batch
        out[b * MW + (start >> 2) + c4] = st[HALO + 4 * c4][b];
    }
}

extern "C" void kernel_launch(void* const* d_in, const int* in_sizes, int n_in,
                              void* d_out, int out_size, void* d_ws, size_t ws_size,
                              hipStream_t stream) {
    const float* x  = (const float*)d_in[0];   // (32, 4096)
    const float* tg = (const float*)d_in[1];   // (8, 32, 16384)
    float* out = (float*)d_out;                // (32, 4096)
    // Differential timing probe: 4 idempotent launches. dur_us - baseline(82)
    // ≈ 3*K + ~6us launch overhead. Same work every call; output correct
    // after the final launch.
    for (int rep = 0; rep < 4; ++rep)
        ASIC_44186623541335_kernel<<<GRID_N / TILE, 512, 0, stream>>>(x, tg, out);
}

// Round 6
// 82.675 us; speedup vs baseline: 1.6641x; 1.6641x over previous
//
#include <hip/hip_runtime.h>

#define GRID_N 16384
#define NLAYERS 8
#define NPOS 32
#define BATCH 32
#define MW 4096          // output width
#define TILE 32
#define HALO 16          // 2 * NLAYERS
#define WBUF 64          // TILE + 2*HALO
#define ROWP 36          // padded row stride: 144B, 16B-aligned

typedef float f2 __attribute__((ext_vector_type(2)));

// v6: packed-fp32 lerp tree (v_pk_fma_f32) + 8 batches/thread.
// 512 blocks x 256 threads (2 blocks/CU, 8 waves/CU). Wave ty owns batches
// 8ty..8ty+7 for all 64 column slots -> state wave-private (no state barriers;
// wave_barrier stops compiler reordering). Gates staged once for 4 layers
// (twl[4]), layers 4..7 register-prefetched; 4 __syncthreads total.
__global__ __launch_bounds__(256, 2) void ASIC_44186623541335_kernel(
    const float* __restrict__ x,    // (32, 4096)
    const float* __restrict__ tg,   // (8, 32, 16384) raw logits
    float* __restrict__ out)        // (32, 4096)
{
    __shared__ __align__(16) float st[WBUF][ROWP];        // 9.2 KB
    __shared__ __align__(16) float twl[4][WBUF][ROWP];    // 36.9 KB

    const int tid = threadIdx.x;
    const int tx  = tid & 63;        // column slot (lane)
    const int ty  = tid >> 6;        // wave 0..3 -> batches 8ty..8ty+7
    const int c0  = 8 * ty;
    const int start = blockIdx.x * TILE;
    const int gcol  = (start - HALO + tx) & (GRID_N - 1);

    // ---- prefetch gate logits for layers 0..3 (coalesced across lanes) ----
    float pf[32];
    #pragma unroll
    for (int l4 = 0; l4 < 4; ++l4)
        #pragma unroll
        for (int k = 0; k < 8; ++k)
            pf[l4 * 8 + k] = tg[((size_t)l4 * NPOS + c0 + k) * GRID_N + gcol];

    // ---- init state: embed x at stride 4, zeros elsewhere ----
    for (int f = tid; f < WBUF * BATCH; f += 256) {
        const int b = f >> 6;
        const int j = f & 63;
        const int g = (start - HALO + j) & (GRID_N - 1);
        st[j][b] = ((g & 3) == 0) ? x[b * MW + (g >> 2)] : 0.0f;
    }

    // ---- stage layers 0..3 (sigmoid once); prefetch layers 4..7 ----
    #pragma unroll
    for (int l4 = 0; l4 < 4; ++l4) {
        #pragma unroll
        for (int h4 = 0; h4 < 2; ++h4) {
            float4 sg;
            sg.x = __builtin_amdgcn_rcpf(1.0f + __expf(-pf[l4 * 8 + 4 * h4 + 0]));
            sg.y = __builtin_amdgcn_rcpf(1.0f + __expf(-pf[l4 * 8 + 4 * h4 + 1]));
            sg.z = __builtin_amdgcn_rcpf(1.0f + __expf(-pf[l4 * 8 + 4 * h4 + 2]));
            sg.w = __builtin_amdgcn_rcpf(1.0f + __expf(-pf[l4 * 8 + 4 * h4 + 3]));
            *(float4*)&twl[l4][tx][c0 + 4 * h4] = sg;
        }
    }
    #pragma unroll
    for (int l4 = 0; l4 < 4; ++l4)
        #pragma unroll
        for (int k = 0; k < 8; ++k)
            pf[l4 * 8 + k] = tg[((size_t)(4 + l4) * NPOS + c0 + k) * GRID_N + gcol];
    __syncthreads();   // barrier 1: gates(0..3) + embedded state visible

    for (int l = 0; l < NLAYERS; ++l) {
        const int h     = 2 * (NLAYERS - 1 - l);
        const int ncols = TILE + 2 * h;          // 60,56,...,32
        const int j     = (HALO - h) + tx;

        if (tx < ncols) {
            // gates for this column -> 32 regs (8x ds_read_b128)
            float tw[32];
            #pragma unroll
            for (int k = 0; k < 8; ++k) {
                const float4 q = *(const float4*)&twl[l & 3][j][4 * k];
                tw[4 * k]     = q.x; tw[4 * k + 1] = q.y;
                tw[4 * k + 2] = q.z; tw[4 * k + 3] = q.w;
            }
            // batch-invariant level-0 diffs (shared across all 8 batches)
            float d0[16];
            #pragma unroll
            for (int r = 0; r < 16; ++r) d0[r] = tw[16 + r] - tw[r];

            // state: 5 neighbor columns x 8 batches (2x b128 each)
            float4 A[5][2];
            #pragma unroll
            for (int o = 0; o < 5; ++o) {
                A[o][0] = *(const float4*)&st[j - 2 + o][c0];
                A[o][1] = *(const float4*)&st[j - 2 + o][c0 + 4];
            }

            float4 res[2];
            #pragma unroll
            for (int q = 0; q < 4; ++q) {        // 4 pairs of batches
                const int hi = q >> 1, lo = (q & 1) * 2;
                const f2 s0 = { ((const float*)&A[0][hi])[lo], ((const float*)&A[0][hi])[lo + 1] };
                const f2 s1 = { ((const float*)&A[1][hi])[lo], ((const float*)&A[1][hi])[lo + 1] };
                const f2 s2 = { ((const float*)&A[2][hi])[lo], ((const float*)&A[2][hi])[lo + 1] };
                const f2 s3 = { ((const float*)&A[3][hi])[lo], ((const float*)&A[3][hi])[lo + 1] };
                const f2 s4 = { ((const float*)&A[4][hi])[lo], ((const float*)&A[4][hi])[lo + 1] };

                // 5-level lerp tree, two batches per packed op (v_pk_fma_f32)
                f2 u[16];
                #pragma unroll
                for (int r = 0; r < 16; ++r)
                    u[r] = __builtin_elementwise_fma(s0, (f2)d0[r], (f2)tw[r]);
                #pragma unroll
                for (int r = 0; r < 8; ++r)
                    u[r] = __builtin_elementwise_fma(s1, u[8 + r] - u[r], u[r]);
                #pragma unroll
                for (int r = 0; r < 4; ++r)
                    u[r] = __builtin_elementwise_fma(s2, u[4 + r] - u[r], u[r]);
                #pragma unroll
                for (int r = 0; r < 2; ++r)
                    u[r] = __builtin_elementwise_fma(s3, u[2 + r] - u[r], u[r]);
                f2 rv = __builtin_elementwise_fma(s4, u[1] - u[0], u[0]);
                rv = __builtin_elementwise_min(__builtin_elementwise_max(rv, (f2)0.0f), (f2)1.0f);
                ((float*)&res[hi])[lo]     = rv.x;
                ((float*)&res[hi])[lo + 1] = rv.y;
            }
            *(float4*)&st[j][c0]     = res[0];   // wave-private slice: no barrier
            *(float4*)&st[j][c0 + 4] = res[1];
        }
        // forbid compiler hoisting next layer's LDS reads above this write;
        // HW executes a wave's DS ops in order, so cross-lane RAW is safe.
        __builtin_amdgcn_wave_barrier();

        if (l == 3) {
            __syncthreads();   // barrier 2: all waves done reading gates(0..3)
            #pragma unroll
            for (int l4 = 0; l4 < 4; ++l4) {
                #pragma unroll
                for (int h4 = 0; h4 < 2; ++h4) {
                    float4 sg;
                    sg.x = __builtin_amdgcn_rcpf(1.0f + __expf(-pf[l4 * 8 + 4 * h4 + 0]));
                    sg.y = __builtin_amdgcn_rcpf(1.0f + __expf(-pf[l4 * 8 + 4 * h4 + 1]));
                    sg.z = __builtin_amdgcn_rcpf(1.0f + __expf(-pf[l4 * 8 + 4 * h4 + 2]));
                    sg.w = __builtin_amdgcn_rcpf(1.0f + __expf(-pf[l4 * 8 + 4 * h4 + 3]));
                    *(float4*)&twl[l4][tx][c0 + 4 * h4] = sg;
                }
            }
            __syncthreads();   // barrier 3: gates(4..7) visible
        }
    }

    __syncthreads();           // barrier 4: final state visible for transposed output
    // ---- output: state[:, ::4] for this tile's 32 owned columns ----
    {
        const int c4 = tid & 7;          // output column within tile
        const int b  = tid >> 3;         // batch
        out[b * MW + (start >> 2) + c4] = st[HALO + 4 * c4][b];
    }
}

extern "C" void kernel_launch(void* const* d_in, const int* in_sizes, int n_in,
                              void* d_out, int out_size, void* d_ws, size_t ws_size,
                              hipStream_t stream) {
    const float* x  = (const float*)d_in[0];   // (32, 4096)
    const float* tg = (const float*)d_in[1];   // (8, 32, 16384)
    float* out = (float*)d_out;                // (32, 4096)
    ASIC_44186623541335_kernel<<<GRID_N / TILE, 256, 0, stream>>>(x, tg, out);
}

// Round 7
// 80.808 us; speedup vs baseline: 1.7025x; 1.0231x over previous
//
#include <hip/hip_runtime.h>

#define GRID_N 16384
#define NLAYERS 8
#define NPOS 32
#define BATCH 32
#define MW 4096          // output width
#define TILE 32
#define HALO 16          // 2 * NLAYERS
#define WBUF 64          // TILE + 2*HALO = one wave of column slots
#define ROWP 36          // gate row stride: 144B, 16B-aligned, uniform bank coverage

typedef float f2 __attribute__((ext_vector_type(2)));

// DPP wave shifts: data from lane n-1 / n+1 (bound lanes read 0).
__device__ __forceinline__ float dpp_shr1(float v) {   // lane n <- lane n-1
    return __builtin_bit_cast(float, __builtin_amdgcn_update_dpp(
        0, __builtin_bit_cast(int, v), 0x138, 0xF, 0xF, true));
}
__device__ __forceinline__ float dpp_shl1(float v) {   // lane n <- lane n+1
    return __builtin_bit_cast(float, __builtin_amdgcn_update_dpp(
        0, __builtin_bit_cast(int, v), 0x130, 0xF, 0xF, true));
}
__device__ __forceinline__ f2 shr1(f2 v) { f2 r; r.x = dpp_shr1(v.x); r.y = dpp_shr1(v.y); return r; }
__device__ __forceinline__ f2 shl1(f2 v) { f2 r; r.x = dpp_shl1(v.x); r.y = dpp_shl1(v.y); return r; }

// v7: state lives in VGPRs (lane = column slot, wave = 8 batches); neighbor
// exchange via DPP wave shifts on the VALU pipe -> ZERO state LDS traffic and
// no write->read LDS latency chain between layers. LDS holds only gates
// (4 layers staged, sigmoid once); 3 barriers total. All 64 lanes compute
// uniformly: halo 16 = 2 cols/layer x 8 layers absorbs edge garbage (DPP
// bound_ctrl feeds edges zeros); interior values are bit-identical.
// 512 blocks x 256 threads, 2 blocks/CU (LDS 36.9 KB), 8 waves/CU.
__global__ __launch_bounds__(256, 2) void ASIC_44186623541335_kernel(
    const float* __restrict__ x,    // (32, 4096)
    const float* __restrict__ tg,   // (8, 32, 16384) raw logits
    float* __restrict__ out)        // (32, 4096)
{
    __shared__ __align__(16) float twl[4][WBUF][ROWP];   // 36.9 KB, gates only

    const int tid = threadIdx.x;
    const int tx  = tid & 63;        // column slot (lane)
    const int ty  = tid >> 6;        // wave 0..3 -> batches 8ty..8ty+7
    const int c0  = 8 * ty;
    const int start = blockIdx.x * TILE;
    const int gcol  = (start - HALO + tx) & (GRID_N - 1);

    // ---- prefetch gate logits for layers 0..3 (coalesced across lanes) ----
    float pf[32];
    #pragma unroll
    for (int l4 = 0; l4 < 4; ++l4)
        #pragma unroll
        for (int k = 0; k < 8; ++k)
            pf[l4 * 8 + k] = tg[((size_t)l4 * NPOS + c0 + k) * GRID_N + gcol];

    // ---- init state IN REGISTERS: embed x at stride 4, zeros elsewhere ----
    f2 S[4];
    {
        const bool on = (gcol & 3) == 0;
        const int  m  = gcol >> 2;
        #pragma unroll
        for (int q = 0; q < 4; ++q) {
            f2 v = {0.0f, 0.0f};
            if (on) {
                v.x = x[(c0 + 2 * q)     * MW + m];
                v.y = x[(c0 + 2 * q + 1) * MW + m];
            }
            S[q] = v;
        }
    }

    // ---- stage layers 0..3 (sigmoid once); prefetch layers 4..7 ----
    #pragma unroll
    for (int l4 = 0; l4 < 4; ++l4) {
        #pragma unroll
        for (int h4 = 0; h4 < 2; ++h4) {
            float4 sg;
            sg.x = __builtin_amdgcn_rcpf(1.0f + __expf(-pf[l4 * 8 + 4 * h4 + 0]));
            sg.y = __builtin_amdgcn_rcpf(1.0f + __expf(-pf[l4 * 8 + 4 * h4 + 1]));
            sg.z = __builtin_amdgcn_rcpf(1.0f + __expf(-pf[l4 * 8 + 4 * h4 + 2]));
            sg.w = __builtin_amdgcn_rcpf(1.0f + __expf(-pf[l4 * 8 + 4 * h4 + 3]));
            *(float4*)&twl[l4][tx][c0 + 4 * h4] = sg;
        }
    }
    #pragma unroll
    for (int l4 = 0; l4 < 4; ++l4)
        #pragma unroll
        for (int k = 0; k < 8; ++k)
            pf[l4 * 8 + k] = tg[((size_t)(4 + l4) * NPOS + c0 + k) * GRID_N + gcol];
    __syncthreads();   // barrier 1: gates(0..3) visible

    for (int l = 0; l < NLAYERS; ++l) {
        // gates for this column -> 32 regs (8x ds_read_b128)
        float tw[32];
        #pragma unroll
        for (int k = 0; k < 8; ++k) {
            const float4 q = *(const float4*)&twl[l & 3][tx][4 * k];
            tw[4 * k]     = q.x; tw[4 * k + 1] = q.y;
            tw[4 * k + 2] = q.z; tw[4 * k + 3] = q.w;
        }
        // batch-invariant level-0 diffs
        float d0[16];
        #pragma unroll
        for (int r = 0; r < 16; ++r) d0[r] = tw[16 + r] - tw[r];

        // neighbor states via DPP wave shifts (VALU pipe, no LDS)
        f2 s0v[4], s1v[4], s3v[4], s4v[4];
        #pragma unroll
        for (int q = 0; q < 4; ++q) {
            s1v[q] = shr1(S[q]);      // column n-1
            s0v[q] = shr1(s1v[q]);    // column n-2
            s3v[q] = shl1(S[q]);      // column n+1
            s4v[q] = shl1(s3v[q]);    // column n+2
        }

        #pragma unroll
        for (int q = 0; q < 4; ++q) {     // pair q = batches c0+2q, c0+2q+1
            // 5-level lerp tree, two batches per packed op
            f2 u[16];
            #pragma unroll
            for (int r = 0; r < 16; ++r)
                u[r] = __builtin_elementwise_fma(s0v[q], (f2)d0[r], (f2)tw[r]);
            #pragma unroll
            for (int r = 0; r < 8; ++r)
                u[r] = __builtin_elementwise_fma(s1v[q], u[8 + r] - u[r], u[r]);
            #pragma unroll
            for (int r = 0; r < 4; ++r)
                u[r] = __builtin_elementwise_fma(S[q], u[4 + r] - u[r], u[r]);   // center
            #pragma unroll
            for (int r = 0; r < 2; ++r)
                u[r] = __builtin_elementwise_fma(s3v[q], u[2 + r] - u[r], u[r]);
            f2 rv = __builtin_elementwise_fma(s4v[q], u[1] - u[0], u[0]);
            rv = __builtin_elementwise_min(__builtin_elementwise_max(rv, (f2)0.0f), (f2)1.0f);
            S[q] = rv;
        }

        if (l == 3) {
            __syncthreads();   // barrier 2: all waves done reading gates(0..3)
            #pragma unroll
            for (int l4 = 0; l4 < 4; ++l4) {
                #pragma unroll
                for (int h4 = 0; h4 < 2; ++h4) {
                    float4 sg;
                    sg.x = __builtin_amdgcn_rcpf(1.0f + __expf(-pf[l4 * 8 + 4 * h4 + 0]));
                    sg.y = __builtin_amdgcn_rcpf(1.0f + __expf(-pf[l4 * 8 + 4 * h4 + 1]));
                    sg.z = __builtin_amdgcn_rcpf(1.0f + __expf(-pf[l4 * 8 + 4 * h4 + 2]));
                    sg.w = __builtin_amdgcn_rcpf(1.0f + __expf(-pf[l4 * 8 + 4 * h4 + 3]));
                    *(float4*)&twl[l4][tx][c0 + 4 * h4] = sg;
                }
            }
            __syncthreads();   // barrier 3: gates(4..7) visible
        }
    }

    // ---- output straight from registers: state[:, ::4] for owned columns ----
    const int rel = tx - HALO;
    if (rel >= 0 && rel < TILE && (rel & 3) == 0) {
        const int m = (start >> 2) + (rel >> 2);
        #pragma unroll
        for (int q = 0; q < 4; ++q) {
            out[(c0 + 2 * q)     * MW + m] = S[q].x;
            out[(c0 + 2 * q + 1) * MW + m] = S[q].y;
        }
    }
}

extern "C" void kernel_launch(void* const* d_in, const int* in_sizes, int n_in,
                              void* d_out, int out_size, void* d_ws, size_t ws_size,
                              hipStream_t stream) {
    const float* x  = (const float*)d_in[0];   // (32, 4096)
    const float* tg = (const float*)d_in[1];   // (8, 32, 16384)
    float* out = (float*)d_out;                // (32, 4096)
    ASIC_44186623541335_kernel<<<GRID_N / TILE, 256, 0, stream>>>(x, tg, out);
}